// Round 1
// baseline (722.900 us; speedup 1.0000x reference)
//
#include <hip/hip_runtime.h>

#define N_NODES 100000
#define N_EDGES 1600000
#define NEG_SLOPE 0.2f
#define BN_EPS 1e-5f

typedef __attribute__((ext_vector_type(8))) short short8;
typedef __attribute__((ext_vector_type(4))) float floatx4;

// ---------------- workspace layout (bytes) ----------------
static const size_t OFF_AB   = 0;            // feats bf16 fragment-ordered [N_PAD,128]
static const size_t OFF_BB   = 25624576;     // weights bf16 fragment-ordered [512,128]
static const size_t OFF_H    = 25755648;     // h bf16 [N+1,256] (row N = sentinel zeros)
static const size_t OFF_RES  = 76956672;     // res+bias bf16 [N,256]
static const size_t OFF_EL   = 128156672;    // el [N+1,4] f32 (row N = -1e30 sentinel)
static const size_t OFF_ER   = 129757184;    // er [N,4] f32
static const size_t OFF_DEG  = 131357184;    // deg [N] i32
static const size_t OFF_RS   = 131757184;    // padded row_start [N+1] i32
static const size_t OFF_CUR  = 132157568;    // cursor [N] i32
static const size_t OFF_ESRC = 132557568;    // padded edge src ids [<=2.4M] i32
static const size_t OFF_BS   = 142157568;    // block sums [128] i32
static const size_t OFF_BN   = 142158080;    // bn accum [128] f32
// total ~142.2 MB

__device__ __forceinline__ unsigned short f2bf(float x) {
  unsigned int u = __float_as_uint(x);
  unsigned int r = (u + 0x7fffu + ((u >> 16) & 1u)) >> 16;   // RNE
  return (unsigned short)r;
}
__device__ __forceinline__ float bf2f(unsigned short u) {
  return __uint_as_float(((unsigned int)u) << 16);
}

// ---------------- fused pre-pass: cvt_a | edge count | cvt_w | sentinels ----
__global__ __launch_bounds__(256) void k_pre(
    const float* __restrict__ feats, const float* __restrict__ fc_w,
    const float* __restrict__ res_w, const int* __restrict__ dst,
    unsigned short* __restrict__ Ab, unsigned short* __restrict__ Bb,
    int* __restrict__ deg, unsigned short* __restrict__ hbuf,
    float* __restrict__ el)
{
  const int b = blockIdx.x;
  if (b < 6256) {                                // ---- cvt_a: N_PAD*16 chunks
    int c = b * 256 + threadIdx.x;
    int r = c >> 4, j = c & 15;
    unsigned short v[8];
    if (r < N_NODES) {
      const float* p = feats + (size_t)r * 128 + j * 8;
      float4 a = *(const float4*)p, bb = *(const float4*)(p + 4);
      v[0]=f2bf(a.x); v[1]=f2bf(a.y); v[2]=f2bf(a.z); v[3]=f2bf(a.w);
      v[4]=f2bf(bb.x); v[5]=f2bf(bb.y); v[6]=f2bf(bb.z); v[7]=f2bf(bb.w);
    } else {
      for (int i = 0; i < 8; i++) v[i] = 0;
    }
    size_t idx = (size_t)(r >> 7) * 2048 + ((r >> 4) & 7) * 256 + (j >> 2) * 64
               + (r & 15) + 16 * (j & 3);
    *(short8*)(Ab + idx * 8) = *(short8*)v;
  } else if (b < 12506) {                        // ---- count degrees
    int e = (b - 6256) * 256 + threadIdx.x;
    if (e < N_EDGES) atomicAdd(&deg[dst[e]], 1);
  } else if (b < 12538) {                        // ---- cvt_w: 8192 chunks
    int c = (b - 12506) * 256 + threadIdx.x;
    int n = c >> 4, j = c & 15;
    const float* W = (n < 256) ? (fc_w + (size_t)n * 128) : (res_w + (size_t)(n - 256) * 128);
    const float* p = W + j * 8;
    float4 a = *(const float4*)p, bb = *(const float4*)(p + 4);
    unsigned short v[8];
    v[0]=f2bf(a.x); v[1]=f2bf(a.y); v[2]=f2bf(a.z); v[3]=f2bf(a.w);
    v[4]=f2bf(bb.x); v[5]=f2bf(bb.y); v[6]=f2bf(bb.z); v[7]=f2bf(bb.w);
    size_t idx = (size_t)(n >> 7) * 2048 + ((n >> 4) & 7) * 256 + (j >> 2) * 64
               + (n & 15) + 16 * (j & 3);
    *(short8*)(Bb + idx * 8) = *(short8*)v;
  } else {                                       // ---- sentinel row init
    const int t = threadIdx.x;
    hbuf[(size_t)N_NODES * 256 + t] = 0;         // zero h row for dummy src
    if (t < 4) el[N_NODES * 4 + t] = -1e30f;     // weight-0 logit for dummy src
  }
}

// ---------------- MFMA projection + fused el/er (unchanged) -----------------
__global__ __launch_bounds__(256) void k_mm(
    const unsigned short* __restrict__ Ab, const unsigned short* __restrict__ Bb,
    const float* __restrict__ bias, const float* __restrict__ attn_l,
    const float* __restrict__ attn_r,
    unsigned short* __restrict__ hbuf, unsigned short* __restrict__ resbuf,
    float* __restrict__ el, float* __restrict__ er)
{
  __shared__ unsigned short sA[16384];  // 32 KB, fragment-ordered A block
  const int tid = threadIdx.x;
  const int w = tid >> 6, L = tid & 63;
  const int blk = blockIdx.x, nb = blockIdx.y;

  {  // stage A: contiguous 32 KB, global_load_lds width 16
    const unsigned short* ga = Ab + (size_t)blk * 16384;
    #pragma unroll
    for (int i = 0; i < 8; i++) {
      int off = (i * 256 + w * 64) * 8;
      __builtin_amdgcn_global_load_lds(
          (const __attribute__((address_space(1))) unsigned int*)(ga + off + L * 8),
          (__attribute__((address_space(3))) unsigned int*)(sA + off),
          16, 0, 0);
    }
  }
  const int mh = w & 1, nh = w >> 1;
  floatx4 acc[4][4] = {};
  __syncthreads();

  const unsigned short* gb = Bb + ((size_t)nb * 2048 + nh * 4 * 256) * 8 + L * 8;
  #pragma unroll
  for (int s = 0; s < 4; s++) {
    short8 a[4], b[4];
    #pragma unroll
    for (int t = 0; t < 4; t++)
      a[t] = *(const short8*)(sA + ((mh * 4 + t) * 256 + s * 64 + L) * 8);
    #pragma unroll
    for (int t = 0; t < 4; t++)
      b[t] = *(const short8*)(gb + ((size_t)t * 256 + s * 64) * 8);
    #pragma unroll
    for (int mt = 0; mt < 4; mt++)
      #pragma unroll
      for (int nt = 0; nt < 4; nt++)
        acc[mt][nt] = __builtin_amdgcn_mfma_f32_16x16x32_bf16(a[mt], b[nt], acc[mt][nt], 0, 0, 0);
  }

  const int q = L >> 4, cn = L & 15;
  const int r0 = blk * 128 + mh * 64;
  if (nb < 2) {
    const int head = nb * 2 + nh;
    const int col0 = nb * 128 + nh * 64;
    float al[4], ar[4];
    #pragma unroll
    for (int nt = 0; nt < 4; nt++) {
      al[nt] = attn_l[head * 64 + nt * 16 + cn];
      ar[nt] = attn_r[head * 64 + nt * 16 + cn];
    }
    #pragma unroll
    for (int mt = 0; mt < 4; mt++)
      #pragma unroll
      for (int r = 0; r < 4; r++) {
        const int row = r0 + mt * 16 + q * 4 + r;
        float pl = 0.f, pr = 0.f;
        #pragma unroll
        for (int nt = 0; nt < 4; nt++) {
          pl = fmaf(acc[mt][nt][r], al[nt], pl);
          pr = fmaf(acc[mt][nt][r], ar[nt], pr);
        }
        #pragma unroll
        for (int o = 1; o < 16; o <<= 1) {
          pl += __shfl_xor(pl, o, 64);
          pr += __shfl_xor(pr, o, 64);
        }
        if (row < N_NODES) {
          #pragma unroll
          for (int nt = 0; nt < 4; nt++)
            hbuf[(size_t)row * 256 + col0 + nt * 16 + cn] = f2bf(acc[mt][nt][r]);
          if (cn == 0) {
            el[row * 4 + head] = pl;
            er[row * 4 + head] = pr;
          }
        }
      }
  } else {
    const int rc0 = (nb - 2) * 128 + nh * 64;
    #pragma unroll
    for (int mt = 0; mt < 4; mt++)
      #pragma unroll
      for (int r = 0; r < 4; r++) {
        const int row = r0 + mt * 16 + q * 4 + r;
        if (row < N_NODES)
          #pragma unroll
          for (int nt = 0; nt < 4; nt++) {
            float v = acc[mt][nt][r] + bias[rc0 + nt * 16 + cn];
            resbuf[(size_t)row * 256 + rc0 + nt * 16 + cn] = f2bf(v);
          }
      }
  }
}

// ---------------- CSR build (rows PADDED to multiples of 8) ----------------
__global__ __launch_bounds__(256) void k_scan1(const int* __restrict__ deg,
                                               int* __restrict__ rs, int* __restrict__ bsums)
{
  __shared__ int tmp[256];
  const int t = threadIdx.x;
  const int base = blockIdx.x * 1024 + t * 4;
  int v0 = 0, v1 = 0, v2 = 0, v3 = 0;
  if (base + 0 < N_NODES) v0 = (deg[base + 0] + 7) & ~7;
  if (base + 1 < N_NODES) v1 = (deg[base + 1] + 7) & ~7;
  if (base + 2 < N_NODES) v2 = (deg[base + 2] + 7) & ~7;
  if (base + 3 < N_NODES) v3 = (deg[base + 3] + 7) & ~7;
  const int tsum = v0 + v1 + v2 + v3;
  tmp[t] = tsum;
  __syncthreads();
  for (int o = 1; o < 256; o <<= 1) {
    int x = (t >= o) ? tmp[t - o] : 0;
    __syncthreads();
    tmp[t] += x;
    __syncthreads();
  }
  const int excl = tmp[t] - tsum;
  if (base + 0 < N_NODES) rs[base + 0] = excl;
  if (base + 1 < N_NODES) rs[base + 1] = excl + v0;
  if (base + 2 < N_NODES) rs[base + 2] = excl + v0 + v1;
  if (base + 3 < N_NODES) rs[base + 3] = excl + v0 + v1 + v2;
  if (t == 255) bsums[blockIdx.x] = tmp[t];
}

// finalize padded offsets + fill pad slots with sentinel src
__global__ __launch_bounds__(256) void k_scan3(int* __restrict__ rs,
                                               const int* __restrict__ bsums,
                                               int* __restrict__ cursor,
                                               const int* __restrict__ deg,
                                               int* __restrict__ esrc)
{
  __shared__ int sb[128];
  const int t = threadIdx.x;
  int raw = 0;
  if (t < 128) { raw = (t < 98) ? bsums[t] : 0; sb[t] = raw; }
  __syncthreads();
  for (int o = 1; o < 128; o <<= 1) {
    int x = (t >= o && t < 128) ? sb[t - o] : 0;
    __syncthreads();
    if (t < 128) sb[t] += x;
    __syncthreads();
  }
  if (t < 128) sb[t] -= raw;   // exclusive
  __syncthreads();
  const int i = blockIdx.x * 256 + t;
  if (i < N_NODES) {
    int v = rs[i] + sb[i >> 10];
    rs[i] = v;
    cursor[i] = v;
    const int d = deg[i];
    const int pd = (d + 7) & ~7;
    for (int j = d; j < pd; j++) esrc[v + j] = N_NODES;   // weight-0 dummies
    if (i == N_NODES - 1) rs[N_NODES] = v + pd;
  }
}

__global__ __launch_bounds__(256) void k_scatter(const int* __restrict__ src,
                                                 const int* __restrict__ dst,
                                                 int* __restrict__ cursor,
                                                 int* __restrict__ esrc)
{
  int e = blockIdx.x * 256 + threadIdx.x;
  if (e >= N_EDGES) return;
  int d = dst[e];
  int pos = atomicAdd(&cursor[d], 1);
  esrc[pos] = src[e];
}

// ---------------- fused softmax + aggregation + residual/ELU/head-mean ------
// one wave per CONTIGUOUS node range; flat padded-CSR stream;
// 3-buffer cyclic software pipeline (gathers 2 batches ahead, sn 3 ahead).
__global__ __launch_bounds__(256, 4) void k_agg(
    const unsigned short* __restrict__ hbuf, const unsigned short* __restrict__ resbuf,
    const float* __restrict__ el, const float* __restrict__ er,
    const int* __restrict__ rs, const int* __restrict__ esrc,
    float* __restrict__ out, float* __restrict__ bn)
{
  const int lane = threadIdx.x & 63;
  const int head = lane >> 4;
  const int wid = blockIdx.x * 4 + (threadIdx.x >> 6);
  const int nW = gridDim.x * 4;
  float4 s4 = make_float4(0.f, 0.f, 0.f, 0.f);
  float4 q4 = make_float4(0.f, 0.f, 0.f, 0.f);

  const int n0 = (int)(((long long)wid * N_NODES) / nW);
  const int n1 = (int)(((long long)(wid + 1) * N_NODES) / nW);

  if (n0 < n1) {
    int nu = __builtin_amdgcn_readfirstlane(n0);
    int nend = __builtin_amdgcn_readfirstlane(rs[nu + 1]);
    const int p_beg = __builtin_amdgcn_readfirstlane(rs[n0]);
    const int p_end = __builtin_amdgcn_readfirstlane(rs[n1]);
    float ern = er[nu * 4 + head];
    float ern_nx = (nu + 1 < N_NODES) ? er[(nu + 1) * 4 + head] : 0.f;
    ushort4 rv_cur = *(const ushort4*)(resbuf + (size_t)nu * 256 + lane * 4);

    float4 acc = make_float4(0.f, 0.f, 0.f, 0.f);
    float ssum = 0.f;

    auto fin = [&](int nd) {
      const float inv = (ssum > 0.f) ? (1.0f / ssum) : 0.f;
      float4 v;
      v.x = fmaf(acc.x, inv, bf2f(rv_cur.x));
      v.y = fmaf(acc.y, inv, bf2f(rv_cur.y));
      v.z = fmaf(acc.z, inv, bf2f(rv_cur.z));
      v.w = fmaf(acc.w, inv, bf2f(rv_cur.w));
      v.x = (v.x > 0.f) ? v.x : (__expf(v.x) - 1.f);
      v.y = (v.y > 0.f) ? v.y : (__expf(v.y) - 1.f);
      v.z = (v.z > 0.f) ? v.z : (__expf(v.z) - 1.f);
      v.w = (v.w > 0.f) ? v.w : (__expf(v.w) - 1.f);
      v.x += __shfl_xor(v.x, 16, 64);  v.x += __shfl_xor(v.x, 32, 64);
      v.y += __shfl_xor(v.y, 16, 64);  v.y += __shfl_xor(v.y, 32, 64);
      v.z += __shfl_xor(v.z, 16, 64);  v.z += __shfl_xor(v.z, 32, 64);
      v.w += __shfl_xor(v.w, 16, 64);  v.w += __shfl_xor(v.w, 32, 64);
      if (lane < 16) {
        v.x *= 0.25f; v.y *= 0.25f; v.z *= 0.25f; v.w *= 0.25f;
        *(float4*)(out + (size_t)nd * 64 + lane * 4) = v;
        s4.x += v.x; s4.y += v.y; s4.z += v.z; s4.w += v.w;
        q4.x += v.x * v.x; q4.y += v.y * v.y; q4.z += v.z * v.z; q4.w += v.w * v.w;
      }
    };

    int sn0[8], sn1[8], sn2[8];
    float ev0[8], ev1[8], ev2[8];
    ushort4 hv0[8], hv1[8], hv2[8];

    int p = p_beg;
    if (p < p_end) {
      #pragma unroll
      for (int i = 0; i < 8; i++) sn0[i] = __builtin_amdgcn_readfirstlane(esrc[p + i]);
      #pragma unroll
      for (int i = 0; i < 8; i++) ev0[i] = el[sn0[i] * 4 + head];
      #pragma unroll
      for (int i = 0; i < 8; i++)
        hv0[i] = *(const ushort4*)(hbuf + (size_t)sn0[i] * 256 + lane * 4);
    }
    if (p + 8 < p_end) {
      #pragma unroll
      for (int i = 0; i < 8; i++) sn1[i] = __builtin_amdgcn_readfirstlane(esrc[p + 8 + i]);
      #pragma unroll
      for (int i = 0; i < 8; i++) ev1[i] = el[sn1[i] * 4 + head];
      #pragma unroll
      for (int i = 0; i < 8; i++)
        hv1[i] = *(const ushort4*)(hbuf + (size_t)sn1[i] * 256 + lane * 4);
    }
    if (p + 16 < p_end) {
      #pragma unroll
      for (int i = 0; i < 8; i++) sn2[i] = __builtin_amdgcn_readfirstlane(esrc[p + 16 + i]);
    }

    auto STEP = [&](int pc, float (&evc)[8], ushort4 (&hvc)[8],
                    float (&evg)[8], ushort4 (&hvg)[8],
                    int (&sng)[8], int (&snl)[8]) {
      if (pc + 16 < p_end) {          // issue gathers for batch pc+16
        #pragma unroll
        for (int i = 0; i < 8; i++) evg[i] = el[sng[i] * 4 + head];
        #pragma unroll
        for (int i = 0; i < 8; i++)
          hvg[i] = *(const ushort4*)(hbuf + (size_t)sng[i] * 256 + lane * 4);
      }
      if (pc + 24 < p_end) {          // load src ids for batch pc+24
        #pragma unroll
        for (int i = 0; i < 8; i++)
          snl[i] = __builtin_amdgcn_readfirstlane(esrc[pc + 24 + i]);
      }
      while (pc == nend) {            // node boundary (batch-aligned by padding)
        fin(nu);
        acc = make_float4(0.f, 0.f, 0.f, 0.f); ssum = 0.f;
        nu++;
        nend = __builtin_amdgcn_readfirstlane(rs[nu + 1]);
        ern = ern_nx;
        rv_cur = *(const ushort4*)(resbuf + (size_t)nu * 256 + lane * 4);
        const int nn = nu + 1;
        ern_nx = (nn < N_NODES) ? er[nn * 4 + head] : 0.f;
      }
      #pragma unroll
      for (int i = 0; i < 8; i++) {   // compute batch pc
        float e = evc[i] + ern;
        e = (e > 0.f) ? e : NEG_SLOPE * e;
        const float w = __expf(e);
        ssum += w;
        acc.x = fmaf(w, bf2f(hvc[i].x), acc.x);
        acc.y = fmaf(w, bf2f(hvc[i].y), acc.y);
        acc.z = fmaf(w, bf2f(hvc[i].z), acc.z);
        acc.w = fmaf(w, bf2f(hvc[i].w), acc.w);
      }
    };

    while (p < p_end) {
      STEP(p, ev0, hv0, ev2, hv2, sn2, sn0); p += 8; if (p >= p_end) break;
      STEP(p, ev1, hv1, ev0, hv0, sn0, sn1); p += 8; if (p >= p_end) break;
      STEP(p, ev2, hv2, ev1, hv1, sn1, sn2); p += 8;
    }
    while (nu < n1) {                 // drain: last node + trailing zero-deg
      fin(nu);
      acc = make_float4(0.f, 0.f, 0.f, 0.f); ssum = 0.f;
      nu++;
      if (nu < n1) rv_cur = *(const ushort4*)(resbuf + (size_t)nu * 256 + lane * 4);
    }
  }

  __shared__ float lsum[64], lsq[64];
  if (threadIdx.x < 64) { lsum[threadIdx.x] = 0.f; lsq[threadIdx.x] = 0.f; }
  __syncthreads();
  if (lane < 16) {
    atomicAdd(&lsum[lane * 4 + 0], s4.x);  atomicAdd(&lsq[lane * 4 + 0], q4.x);
    atomicAdd(&lsum[lane * 4 + 1], s4.y);  atomicAdd(&lsq[lane * 4 + 1], q4.y);
    atomicAdd(&lsum[lane * 4 + 2], s4.z);  atomicAdd(&lsq[lane * 4 + 2], q4.z);
    atomicAdd(&lsum[lane * 4 + 3], s4.w);  atomicAdd(&lsq[lane * 4 + 3], q4.w);
  }
  __syncthreads();
  if (threadIdx.x < 64) {
    atomicAdd(&bn[threadIdx.x], lsum[threadIdx.x]);
    atomicAdd(&bn[64 + threadIdx.x], lsq[threadIdx.x]);
  }
}

// ---------------- batchnorm (stats folded in) ----------------
__global__ __launch_bounds__(256) void k_bn_apply(float* __restrict__ out,
                                                  const float* __restrict__ bn,
                                                  const float* __restrict__ gamma,
                                                  const float* __restrict__ beta)
{
  __shared__ float sc[64], sh[64];
  const int t = threadIdx.x;
  if (t < 64) {
    float mean = bn[t] * (1.0f / N_NODES);
    float var = bn[64 + t] * (1.0f / N_NODES) - mean * mean;
    float s = gamma[t] * rsqrtf(var + BN_EPS);
    sc[t] = s;
    sh[t] = beta[t] - mean * s;
  }
  __syncthreads();
  const int i = blockIdx.x * 256 + t;
  if (i >= N_NODES * 16) return;
  const int d0 = (i & 15) * 4;
  float4 v = *(float4*)(out + (size_t)i * 4);
  v.x = fmaf(v.x, sc[d0 + 0], sh[d0 + 0]);
  v.y = fmaf(v.y, sc[d0 + 1], sh[d0 + 1]);
  v.z = fmaf(v.z, sc[d0 + 2], sh[d0 + 2]);
  v.w = fmaf(v.w, sc[d0 + 3], sh[d0 + 3]);
  *(float4*)(out + (size_t)i * 4) = v;
}

extern "C" void kernel_launch(void* const* d_in, const int* in_sizes, int n_in,
                              void* d_out, int out_size, void* d_ws, size_t ws_size,
                              hipStream_t stream)
{
  const float* feats  = (const float*)d_in[0];
  const int*   src    = (const int*)d_in[1];
  const int*   dst    = (const int*)d_in[2];
  const float* fc_w   = (const float*)d_in[3];
  const float* attn_l = (const float*)d_in[4];
  const float* attn_r = (const float*)d_in[5];
  const float* res_w  = (const float*)d_in[6];
  const float* bias   = (const float*)d_in[7];
  const float* gamma  = (const float*)d_in[8];
  const float* beta   = (const float*)d_in[9];

  char* ws = (char*)d_ws;
  unsigned short* Ab     = (unsigned short*)(ws + OFF_AB);
  unsigned short* Bb     = (unsigned short*)(ws + OFF_BB);
  unsigned short* hbuf   = (unsigned short*)(ws + OFF_H);
  unsigned short* resbuf = (unsigned short*)(ws + OFF_RES);
  float* elb    = (float*)(ws + OFF_EL);
  float* erb    = (float*)(ws + OFF_ER);
  int*   deg    = (int*)(ws + OFF_DEG);
  int*   rsb    = (int*)(ws + OFF_RS);
  int*   curb   = (int*)(ws + OFF_CUR);
  int*   esrc   = (int*)(ws + OFF_ESRC);
  int*   bsums  = (int*)(ws + OFF_BS);
  float* bnb    = (float*)(ws + OFF_BN);
  float* outp   = (float*)d_out;

  hipMemsetAsync(deg, 0, N_NODES * sizeof(int), stream);
  hipMemsetAsync(bnb, 0, 128 * sizeof(float), stream);

  k_pre<<<12539, 256, 0, stream>>>(feats, fc_w, res_w, dst, Ab, Bb, deg, hbuf, elb);
  k_mm<<<dim3(782, 4), 256, 0, stream>>>(Ab, Bb, bias, attn_l, attn_r,
                                         hbuf, resbuf, elb, erb);
  k_scan1<<<98, 256, 0, stream>>>(deg, rsb, bsums);
  k_scan3<<<391, 256, 0, stream>>>(rsb, bsums, curb, deg, esrc);
  k_scatter<<<6250, 256, 0, stream>>>(src, dst, curb, esrc);
  k_agg<<<2048, 256, 0, stream>>>(hbuf, resbuf, elb, erb, rsb, esrc, outp, bnb);
  k_bn_apply<<<6250, 256, 0, stream>>>(outp, bnb, gamma, beta);
}

// Round 2
// 515.863 us; speedup vs baseline: 1.4013x; 1.4013x over previous
//
#include <hip/hip_runtime.h>

#define N_NODES 100000
#define N_EDGES 1600000
#define NEG_SLOPE 0.2f
#define BN_EPS 1e-5f

typedef __attribute__((ext_vector_type(8))) short short8;
typedef __attribute__((ext_vector_type(4))) float floatx4;

// ---------------- workspace layout (bytes) ----------------
static const size_t OFF_AB   = 0;            // feats bf16 fragment-ordered [N_PAD,128]
static const size_t OFF_BB   = 25624576;     // weights bf16 fragment-ordered [512,128]
static const size_t OFF_H    = 25755648;     // h bf16 [N+1,256] (row N = sentinel zeros)
static const size_t OFF_RES  = 76956672;     // res+bias bf16 [N,256]
static const size_t OFF_EL   = 128156672;    // el [N+1,4] f32 (row N = -1e30 sentinel)
static const size_t OFF_ER   = 129757184;    // er [N,4] f32
static const size_t OFF_DEG  = 131357184;    // deg [N] i32
static const size_t OFF_RS   = 131757184;    // padded row_start [N+1] i32
static const size_t OFF_CUR  = 132157568;    // cursor [N] i32
static const size_t OFF_ESRC = 132557568;    // padded edge src ids [<=2.0M] i32
static const size_t OFF_BS   = 142157568;    // block sums [128] i32
static const size_t OFF_BN   = 142158080;    // bn accum [128] f32
// total ~142.2 MB

__device__ __forceinline__ unsigned short f2bf(float x) {
  unsigned int u = __float_as_uint(x);
  unsigned int r = (u + 0x7fffu + ((u >> 16) & 1u)) >> 16;   // RNE
  return (unsigned short)r;
}
__device__ __forceinline__ float bf2f(unsigned short u) {
  return __uint_as_float(((unsigned int)u) << 16);
}

// ---------------- fused pre-pass: cvt_a | edge count | cvt_w | sentinels ----
__global__ __launch_bounds__(256) void k_pre(
    const float* __restrict__ feats, const float* __restrict__ fc_w,
    const float* __restrict__ res_w, const int* __restrict__ dst,
    unsigned short* __restrict__ Ab, unsigned short* __restrict__ Bb,
    int* __restrict__ deg, unsigned short* __restrict__ hbuf,
    float* __restrict__ el)
{
  const int b = blockIdx.x;
  if (b < 6256) {                                // ---- cvt_a: N_PAD*16 chunks
    int c = b * 256 + threadIdx.x;
    int r = c >> 4, j = c & 15;
    unsigned short v[8];
    if (r < N_NODES) {
      const float* p = feats + (size_t)r * 128 + j * 8;
      float4 a = *(const float4*)p, bb = *(const float4*)(p + 4);
      v[0]=f2bf(a.x); v[1]=f2bf(a.y); v[2]=f2bf(a.z); v[3]=f2bf(a.w);
      v[4]=f2bf(bb.x); v[5]=f2bf(bb.y); v[6]=f2bf(bb.z); v[7]=f2bf(bb.w);
    } else {
      for (int i = 0; i < 8; i++) v[i] = 0;
    }
    size_t idx = (size_t)(r >> 7) * 2048 + ((r >> 4) & 7) * 256 + (j >> 2) * 64
               + (r & 15) + 16 * (j & 3);
    *(short8*)(Ab + idx * 8) = *(short8*)v;
  } else if (b < 12506) {                        // ---- count degrees
    int e = (b - 6256) * 256 + threadIdx.x;
    if (e < N_EDGES) atomicAdd(&deg[dst[e]], 1);
  } else if (b < 12538) {                        // ---- cvt_w: 8192 chunks
    int c = (b - 12506) * 256 + threadIdx.x;
    int n = c >> 4, j = c & 15;
    const float* W = (n < 256) ? (fc_w + (size_t)n * 128) : (res_w + (size_t)(n - 256) * 128);
    const float* p = W + j * 8;
    float4 a = *(const float4*)p, bb = *(const float4*)(p + 4);
    unsigned short v[8];
    v[0]=f2bf(a.x); v[1]=f2bf(a.y); v[2]=f2bf(a.z); v[3]=f2bf(a.w);
    v[4]=f2bf(bb.x); v[5]=f2bf(bb.y); v[6]=f2bf(bb.z); v[7]=f2bf(bb.w);
    size_t idx = (size_t)(n >> 7) * 2048 + ((n >> 4) & 7) * 256 + (j >> 2) * 64
               + (n & 15) + 16 * (j & 3);
    *(short8*)(Bb + idx * 8) = *(short8*)v;
  } else {                                       // ---- sentinel row init
    const int t = threadIdx.x;
    hbuf[(size_t)N_NODES * 256 + t] = 0;         // zero h row for dummy src
    if (t < 4) el[N_NODES * 4 + t] = -1e30f;     // weight-0 logit for dummy src
  }
}

// ---------------- MFMA projection + fused el/er (unchanged) -----------------
__global__ __launch_bounds__(256) void k_mm(
    const unsigned short* __restrict__ Ab, const unsigned short* __restrict__ Bb,
    const float* __restrict__ bias, const float* __restrict__ attn_l,
    const float* __restrict__ attn_r,
    unsigned short* __restrict__ hbuf, unsigned short* __restrict__ resbuf,
    float* __restrict__ el, float* __restrict__ er)
{
  __shared__ unsigned short sA[16384];  // 32 KB, fragment-ordered A block
  const int tid = threadIdx.x;
  const int w = tid >> 6, L = tid & 63;
  const int blk = blockIdx.x, nb = blockIdx.y;

  {  // stage A: contiguous 32 KB, global_load_lds width 16
    const unsigned short* ga = Ab + (size_t)blk * 16384;
    #pragma unroll
    for (int i = 0; i < 8; i++) {
      int off = (i * 256 + w * 64) * 8;
      __builtin_amdgcn_global_load_lds(
          (const __attribute__((address_space(1))) unsigned int*)(ga + off + L * 8),
          (__attribute__((address_space(3))) unsigned int*)(sA + off),
          16, 0, 0);
    }
  }
  const int mh = w & 1, nh = w >> 1;
  floatx4 acc[4][4] = {};
  __syncthreads();

  const unsigned short* gb = Bb + ((size_t)nb * 2048 + nh * 4 * 256) * 8 + L * 8;
  #pragma unroll
  for (int s = 0; s < 4; s++) {
    short8 a[4], b[4];
    #pragma unroll
    for (int t = 0; t < 4; t++)
      a[t] = *(const short8*)(sA + ((mh * 4 + t) * 256 + s * 64 + L) * 8);
    #pragma unroll
    for (int t = 0; t < 4; t++)
      b[t] = *(const short8*)(gb + ((size_t)t * 256 + s * 64) * 8);
    #pragma unroll
    for (int mt = 0; mt < 4; mt++)
      #pragma unroll
      for (int nt = 0; nt < 4; nt++)
        acc[mt][nt] = __builtin_amdgcn_mfma_f32_16x16x32_bf16(a[mt], b[nt], acc[mt][nt], 0, 0, 0);
  }

  const int q = L >> 4, cn = L & 15;
  const int r0 = blk * 128 + mh * 64;
  if (nb < 2) {
    const int head = nb * 2 + nh;
    const int col0 = nb * 128 + nh * 64;
    float al[4], ar[4];
    #pragma unroll
    for (int nt = 0; nt < 4; nt++) {
      al[nt] = attn_l[head * 64 + nt * 16 + cn];
      ar[nt] = attn_r[head * 64 + nt * 16 + cn];
    }
    #pragma unroll
    for (int mt = 0; mt < 4; mt++)
      #pragma unroll
      for (int r = 0; r < 4; r++) {
        const int row = r0 + mt * 16 + q * 4 + r;
        float pl = 0.f, pr = 0.f;
        #pragma unroll
        for (int nt = 0; nt < 4; nt++) {
          pl = fmaf(acc[mt][nt][r], al[nt], pl);
          pr = fmaf(acc[mt][nt][r], ar[nt], pr);
        }
        #pragma unroll
        for (int o = 1; o < 16; o <<= 1) {
          pl += __shfl_xor(pl, o, 64);
          pr += __shfl_xor(pr, o, 64);
        }
        if (row < N_NODES) {
          #pragma unroll
          for (int nt = 0; nt < 4; nt++)
            hbuf[(size_t)row * 256 + col0 + nt * 16 + cn] = f2bf(acc[mt][nt][r]);
          if (cn == 0) {
            el[row * 4 + head] = pl;
            er[row * 4 + head] = pr;
          }
        }
      }
  } else {
    const int rc0 = (nb - 2) * 128 + nh * 64;
    #pragma unroll
    for (int mt = 0; mt < 4; mt++)
      #pragma unroll
      for (int r = 0; r < 4; r++) {
        const int row = r0 + mt * 16 + q * 4 + r;
        if (row < N_NODES)
          #pragma unroll
          for (int nt = 0; nt < 4; nt++) {
            float v = acc[mt][nt][r] + bias[rc0 + nt * 16 + cn];
            resbuf[(size_t)row * 256 + rc0 + nt * 16 + cn] = f2bf(v);
          }
      }
  }
}

// ---------------- CSR build (rows PADDED to multiples of 4) ----------------
__global__ __launch_bounds__(256) void k_scan1(const int* __restrict__ deg,
                                               int* __restrict__ rs, int* __restrict__ bsums)
{
  __shared__ int tmp[256];
  const int t = threadIdx.x;
  const int base = blockIdx.x * 1024 + t * 4;
  int v0 = 0, v1 = 0, v2 = 0, v3 = 0;
  if (base + 0 < N_NODES) v0 = (deg[base + 0] + 3) & ~3;
  if (base + 1 < N_NODES) v1 = (deg[base + 1] + 3) & ~3;
  if (base + 2 < N_NODES) v2 = (deg[base + 2] + 3) & ~3;
  if (base + 3 < N_NODES) v3 = (deg[base + 3] + 3) & ~3;
  const int tsum = v0 + v1 + v2 + v3;
  tmp[t] = tsum;
  __syncthreads();
  for (int o = 1; o < 256; o <<= 1) {
    int x = (t >= o) ? tmp[t - o] : 0;
    __syncthreads();
    tmp[t] += x;
    __syncthreads();
  }
  const int excl = tmp[t] - tsum;
  if (base + 0 < N_NODES) rs[base + 0] = excl;
  if (base + 1 < N_NODES) rs[base + 1] = excl + v0;
  if (base + 2 < N_NODES) rs[base + 2] = excl + v0 + v1;
  if (base + 3 < N_NODES) rs[base + 3] = excl + v0 + v1 + v2;
  if (t == 255) bsums[blockIdx.x] = tmp[t];
}

// finalize padded offsets + fill pad slots with sentinel src
__global__ __launch_bounds__(256) void k_scan3(int* __restrict__ rs,
                                               const int* __restrict__ bsums,
                                               int* __restrict__ cursor,
                                               const int* __restrict__ deg,
                                               int* __restrict__ esrc)
{
  __shared__ int sb[128];
  const int t = threadIdx.x;
  int raw = 0;
  if (t < 128) { raw = (t < 98) ? bsums[t] : 0; sb[t] = raw; }
  __syncthreads();
  for (int o = 1; o < 128; o <<= 1) {
    int x = (t >= o && t < 128) ? sb[t - o] : 0;
    __syncthreads();
    if (t < 128) sb[t] += x;
    __syncthreads();
  }
  if (t < 128) sb[t] -= raw;   // exclusive
  __syncthreads();
  const int i = blockIdx.x * 256 + t;
  if (i < N_NODES) {
    int v = rs[i] + sb[i >> 10];
    rs[i] = v;
    cursor[i] = v;
    const int d = deg[i];
    const int pd = (d + 3) & ~3;
    for (int j = d; j < pd; j++) esrc[v + j] = N_NODES;   // weight-0 dummies
    if (i == N_NODES - 1) rs[N_NODES] = v + pd;
  }
}

__global__ __launch_bounds__(256) void k_scatter(const int* __restrict__ src,
                                                 const int* __restrict__ dst,
                                                 int* __restrict__ cursor,
                                                 int* __restrict__ esrc)
{
  int e = blockIdx.x * 256 + threadIdx.x;
  if (e >= N_EDGES) return;
  int d = dst[e];
  int pos = atomicAdd(&cursor[d], 1);
  esrc[pos] = src[e];
}

// ---------------- fused softmax + aggregation + residual/ELU/head-mean ------
// Flat padded-CSR stream per wave (contiguous node range), 4-wide batches,
// depth-4 software pipeline with NAMED registers only (no arrays, no lambdas
// -> nothing the compiler can demote to scratch; round-1 spilled 620 MB).
#define RFL(x) __builtin_amdgcn_readfirstlane(x)

#define LOADSN4(SN, PP) do { SN = *(const int4*)(esrc + (PP)); } while (0)

#define GATHER4(EV, HV, SN) do { \
  const int g0_ = RFL(SN.x), g1_ = RFL(SN.y), g2_ = RFL(SN.z), g3_ = RFL(SN.w); \
  HV##0 = *(const ushort4*)(hbuf + (size_t)g0_ * 256 + lane4); \
  HV##1 = *(const ushort4*)(hbuf + (size_t)g1_ * 256 + lane4); \
  HV##2 = *(const ushort4*)(hbuf + (size_t)g2_ * 256 + lane4); \
  HV##3 = *(const ushort4*)(hbuf + (size_t)g3_ * 256 + lane4); \
  EV##0 = el[g0_ * 4 + head]; \
  EV##1 = el[g1_ * 4 + head]; \
  EV##2 = el[g2_ * 4 + head]; \
  EV##3 = el[g3_ * 4 + head]; \
} while (0)

#define EDGE1(EVi, HVi) do { \
  float e_ = EVi + ern; \
  e_ = (e_ > 0.f) ? e_ : NEG_SLOPE * e_; \
  const float w_ = __expf(e_); \
  ssum += w_; \
  acc.x = fmaf(w_, bf2f(HVi.x), acc.x); \
  acc.y = fmaf(w_, bf2f(HVi.y), acc.y); \
  acc.z = fmaf(w_, bf2f(HVi.z), acc.z); \
  acc.w = fmaf(w_, bf2f(HVi.w), acc.w); \
} while (0)

#define COMPUTE4(EV, HV) do { \
  EDGE1(EV##0, HV##0); EDGE1(EV##1, HV##1); \
  EDGE1(EV##2, HV##2); EDGE1(EV##3, HV##3); \
} while (0)

#define FIN(ND) do { \
  const float inv_ = (ssum > 0.f) ? (1.0f / ssum) : 0.f; \
  float vx_ = fmaf(acc.x, inv_, bf2f(rv_cur.x)); \
  float vy_ = fmaf(acc.y, inv_, bf2f(rv_cur.y)); \
  float vz_ = fmaf(acc.z, inv_, bf2f(rv_cur.z)); \
  float vw_ = fmaf(acc.w, inv_, bf2f(rv_cur.w)); \
  vx_ = (vx_ > 0.f) ? vx_ : (__expf(vx_) - 1.f); \
  vy_ = (vy_ > 0.f) ? vy_ : (__expf(vy_) - 1.f); \
  vz_ = (vz_ > 0.f) ? vz_ : (__expf(vz_) - 1.f); \
  vw_ = (vw_ > 0.f) ? vw_ : (__expf(vw_) - 1.f); \
  vx_ += __shfl_xor(vx_, 16, 64); vx_ += __shfl_xor(vx_, 32, 64); \
  vy_ += __shfl_xor(vy_, 16, 64); vy_ += __shfl_xor(vy_, 32, 64); \
  vz_ += __shfl_xor(vz_, 16, 64); vz_ += __shfl_xor(vz_, 32, 64); \
  vw_ += __shfl_xor(vw_, 16, 64); vw_ += __shfl_xor(vw_, 32, 64); \
  if (lane < 16) { \
    float4 o_; \
    o_.x = vx_ * 0.25f; o_.y = vy_ * 0.25f; o_.z = vz_ * 0.25f; o_.w = vw_ * 0.25f; \
    *(float4*)(out + (size_t)(ND) * 64 + lane4) = o_; \
  } \
} while (0)

#define BOUNDARY() \
  while (p == nend) { \
    FIN(nu); \
    acc.x = 0.f; acc.y = 0.f; acc.z = 0.f; acc.w = 0.f; ssum = 0.f; \
    nu++; \
    nend = nendN; ern = ernN; rv_cur = rvN; \
    const int f1_ = (nu + 1 < N_NODES) ? (nu + 1) : (N_NODES - 1); \
    const int f2_ = (nu + 2 <= N_NODES) ? (nu + 2) : N_NODES; \
    nendN = RFL(rs[f2_]); \
    ernN = er[f1_ * 4 + head]; \
    rvN = *(const ushort4*)(resbuf + (size_t)f1_ * 256 + lane4); \
  }

__global__ __launch_bounds__(256, 4) void k_agg(
    const unsigned short* __restrict__ hbuf, const unsigned short* __restrict__ resbuf,
    const float* __restrict__ el, const float* __restrict__ er,
    const int* __restrict__ rs, const int* __restrict__ esrc,
    float* __restrict__ out)
{
  const int lane = threadIdx.x & 63;
  const int head = lane >> 4;
  const int lane4 = lane * 4;
  const int wid = blockIdx.x * 4 + (threadIdx.x >> 6);
  const int nW = gridDim.x * 4;

  const int n0 = (int)(((long long)wid * N_NODES) / nW);
  const int n1 = (int)(((long long)(wid + 1) * N_NODES) / nW);
  if (n0 >= n1) return;

  int nu = RFL(n0);
  const int p_end = RFL(rs[n1]);
  int nend = RFL(rs[nu + 1]);
  {
    // nothing
  }
  int f1 = (nu + 1 < N_NODES) ? (nu + 1) : (N_NODES - 1);
  int f2 = (nu + 2 <= N_NODES) ? (nu + 2) : N_NODES;
  int nendN = RFL(rs[f2]);
  float ern  = er[nu * 4 + head];
  float ernN = er[f1 * 4 + head];
  ushort4 rv_cur = *(const ushort4*)(resbuf + (size_t)nu * 256 + lane4);
  ushort4 rvN    = *(const ushort4*)(resbuf + (size_t)f1 * 256 + lane4);

  float4 acc = make_float4(0.f, 0.f, 0.f, 0.f);
  float ssum = 0.f;

  int4 snA, snB, snC, snD;
  float evA0, evA1, evA2, evA3, evB0, evB1, evB2, evB3;
  float evC0, evC1, evC2, evC3, evD0, evD1, evD2, evD3;
  ushort4 hvA0, hvA1, hvA2, hvA3, hvB0, hvB1, hvB2, hvB3;
  ushort4 hvC0, hvC1, hvC2, hvC3, hvD0, hvD1, hvD2, hvD3;

  int p = RFL(rs[nu]);
  if (p      < p_end) { LOADSN4(snA, p);      GATHER4(evA, hvA, snA); }
  if (p + 4  < p_end) { LOADSN4(snB, p + 4);  GATHER4(evB, hvB, snB); }
  if (p + 8  < p_end) { LOADSN4(snC, p + 8);  GATHER4(evC, hvC, snC); }
  if (p + 12 < p_end) { LOADSN4(snD, p + 12); }

  while (p < p_end) {
    // ---- step A (batch p)
    if (p + 12 < p_end) GATHER4(evD, hvD, snD);
    if (p + 16 < p_end) LOADSN4(snA, p + 16);
    BOUNDARY();
    COMPUTE4(evA, hvA);
    p += 4; if (p >= p_end) break;
    // ---- step B
    if (p + 12 < p_end) GATHER4(evA, hvA, snA);
    if (p + 16 < p_end) LOADSN4(snB, p + 16);
    BOUNDARY();
    COMPUTE4(evB, hvB);
    p += 4; if (p >= p_end) break;
    // ---- step C
    if (p + 12 < p_end) GATHER4(evB, hvB, snB);
    if (p + 16 < p_end) LOADSN4(snC, p + 16);
    BOUNDARY();
    COMPUTE4(evC, hvC);
    p += 4; if (p >= p_end) break;
    // ---- step D
    if (p + 12 < p_end) GATHER4(evC, hvC, snC);
    if (p + 16 < p_end) LOADSN4(snD, p + 16);
    BOUNDARY();
    COMPUTE4(evD, hvD);
    p += 4;
  }

  // drain: finalize last node + trailing zero-degree nodes
  while (nu < n1) {
    FIN(nu);
    acc.x = 0.f; acc.y = 0.f; acc.z = 0.f; acc.w = 0.f; ssum = 0.f;
    nu++;
    if (nu < n1) rv_cur = *(const ushort4*)(resbuf + (size_t)nu * 256 + lane4);
  }
}

// ---------------- BN stats over out (separate small pass) ----------------
__global__ __launch_bounds__(256) void k_bn_stats(const float* __restrict__ out,
                                                  float* __restrict__ bn)
{
  const int t = threadIdx.x;
  const int c4 = (t & 15) * 4;
  const int rg = t >> 4;
  float4 s = make_float4(0.f, 0.f, 0.f, 0.f);
  float4 q = make_float4(0.f, 0.f, 0.f, 0.f);
  for (int row = blockIdx.x * 16 + rg; row < N_NODES; row += gridDim.x * 16) {
    float4 v = *(const float4*)(out + (size_t)row * 64 + c4);
    s.x += v.x; s.y += v.y; s.z += v.z; s.w += v.w;
    q.x += v.x * v.x; q.y += v.y * v.y; q.z += v.z * v.z; q.w += v.w * v.w;
  }
  __shared__ float ls[64], lq[64];
  if (t < 64) { ls[t] = 0.f; lq[t] = 0.f; }
  __syncthreads();
  atomicAdd(&ls[c4 + 0], s.x); atomicAdd(&ls[c4 + 1], s.y);
  atomicAdd(&ls[c4 + 2], s.z); atomicAdd(&ls[c4 + 3], s.w);
  atomicAdd(&lq[c4 + 0], q.x); atomicAdd(&lq[c4 + 1], q.y);
  atomicAdd(&lq[c4 + 2], q.z); atomicAdd(&lq[c4 + 3], q.w);
  __syncthreads();
  if (t < 64) {
    atomicAdd(&bn[t], ls[t]);
    atomicAdd(&bn[64 + t], lq[t]);
  }
}

// ---------------- batchnorm apply ----------------
__global__ __launch_bounds__(256) void k_bn_apply(float* __restrict__ out,
                                                  const float* __restrict__ bn,
                                                  const float* __restrict__ gamma,
                                                  const float* __restrict__ beta)
{
  __shared__ float sc[64], sh[64];
  const int t = threadIdx.x;
  if (t < 64) {
    float mean = bn[t] * (1.0f / N_NODES);
    float var = bn[64 + t] * (1.0f / N_NODES) - mean * mean;
    float s = gamma[t] * rsqrtf(var + BN_EPS);
    sc[t] = s;
    sh[t] = beta[t] - mean * s;
  }
  __syncthreads();
  const int i = blockIdx.x * 256 + t;
  if (i >= N_NODES * 16) return;
  const int d0 = (i & 15) * 4;
  float4 v = *(float4*)(out + (size_t)i * 4);
  v.x = fmaf(v.x, sc[d0 + 0], sh[d0 + 0]);
  v.y = fmaf(v.y, sc[d0 + 1], sh[d0 + 1]);
  v.z = fmaf(v.z, sc[d0 + 2], sh[d0 + 2]);
  v.w = fmaf(v.w, sc[d0 + 3], sh[d0 + 3]);
  *(float4*)(out + (size_t)i * 4) = v;
}

extern "C" void kernel_launch(void* const* d_in, const int* in_sizes, int n_in,
                              void* d_out, int out_size, void* d_ws, size_t ws_size,
                              hipStream_t stream)
{
  const float* feats  = (const float*)d_in[0];
  const int*   src    = (const int*)d_in[1];
  const int*   dst    = (const int*)d_in[2];
  const float* fc_w   = (const float*)d_in[3];
  const float* attn_l = (const float*)d_in[4];
  const float* attn_r = (const float*)d_in[5];
  const float* res_w  = (const float*)d_in[6];
  const float* bias   = (const float*)d_in[7];
  const float* gamma  = (const float*)d_in[8];
  const float* beta   = (const float*)d_in[9];

  char* ws = (char*)d_ws;
  unsigned short* Ab     = (unsigned short*)(ws + OFF_AB);
  unsigned short* Bb     = (unsigned short*)(ws + OFF_BB);
  unsigned short* hbuf   = (unsigned short*)(ws + OFF_H);
  unsigned short* resbuf = (unsigned short*)(ws + OFF_RES);
  float* elb    = (float*)(ws + OFF_EL);
  float* erb    = (float*)(ws + OFF_ER);
  int*   deg    = (int*)(ws + OFF_DEG);
  int*   rsb    = (int*)(ws + OFF_RS);
  int*   curb   = (int*)(ws + OFF_CUR);
  int*   esrc   = (int*)(ws + OFF_ESRC);
  int*   bsums  = (int*)(ws + OFF_BS);
  float* bnb    = (float*)(ws + OFF_BN);
  float* outp   = (float*)d_out;

  hipMemsetAsync(deg, 0, N_NODES * sizeof(int), stream);
  hipMemsetAsync(bnb, 0, 128 * sizeof(float), stream);

  k_pre<<<12539, 256, 0, stream>>>(feats, fc_w, res_w, dst, Ab, Bb, deg, hbuf, elb);
  k_mm<<<dim3(782, 4), 256, 0, stream>>>(Ab, Bb, bias, attn_l, attn_r,
                                         hbuf, resbuf, elb, erb);
  k_scan1<<<98, 256, 0, stream>>>(deg, rsb, bsums);
  k_scan3<<<391, 256, 0, stream>>>(rsb, bsums, curb, deg, esrc);
  k_scatter<<<6250, 256, 0, stream>>>(src, dst, curb, esrc);
  k_agg<<<2048, 256, 0, stream>>>(hbuf, resbuf, elb, erb, rsb, esrc, outp);
  k_bn_stats<<<256, 256, 0, stream>>>(outp, bnb);
  k_bn_apply<<<6250, 256, 0, stream>>>(outp, bnb, gamma, beta);
}